// Round 3
// baseline (4043.251 us; speedup 1.0000x reference)
//
#include <hip/hip_runtime.h>
#include <math.h>

#define N_NODES 60
#define N_EDGES 1800
#define N_ETOT  1860
#define SLOPE   0.2f

// ---------------- LDS union: conv path vs gnn path (block 0) ----------------
// conv layout: simg[2 img][3 ic][32 y][32 x]  (6144 f)
//              c1  [2 img][6 ic][14 y][16 x]  (2688 f, x padded 14->16)
struct ConvS {
    float simg[2 * 3 * 32 * 32];
    float c1[2 * 6 * 14 * 16];
    float pad[16];               // absorbs halo over-reads
};
struct GnnS {
    float ea[N_ETOT];
    float alpha[N_ETOT];         // becomes exp() in place
    float x_in[960];
    float xl[960];
    float outb[960];
    float as_[N_NODES], ad_[N_NODES], den_[N_NODES];
    float red[256];
    unsigned char srcs[N_ETOT], dsts[N_ETOT];
    unsigned short csr[N_ETOT];
    int cnt[N_NODES], off[N_NODES + 4];
};
union SMem { ConvS c; GnnS g; };

__device__ __forceinline__ void block_reduce_sum(float v, float* red, float* out) {
    int tid = threadIdx.x;
    red[tid] = v;
    __syncthreads();
    for (int st = 128; st > 0; st >>= 1) {
        if (tid < st) red[tid] += red[tid + st];
        __syncthreads();
    }
    *out = red[0];
    __syncthreads();
}

__device__ void gat_layer(GnnS& S, const float* x_in, int in_dim, int out_dim,
                          const float* W, const float* a_src, const float* a_dst,
                          const float* We, const float* a_edge, const float* bias,
                          float* xl, float* outb) {
    const int tid = threadIdx.x, nt = blockDim.x;
    for (int idx = tid; idx < N_NODES * out_dim; idx += nt) {
        int i = idx / out_dim, j = idx % out_dim;
        float s = 0.f;
        for (int k = 0; k < in_dim; ++k) s += x_in[i * in_dim + k] * W[k * out_dim + j];
        xl[idx] = s;
    }
    __syncthreads();
    for (int i = tid; i < N_NODES; i += nt) {
        float s = 0.f, d = 0.f;
        for (int j = 0; j < out_dim; ++j) {
            s += xl[i * out_dim + j] * a_src[j];
            d += xl[i * out_dim + j] * a_dst[j];
        }
        S.as_[i] = s; S.ad_[i] = d;
    }
    float ecoef = 0.f;
    for (int j = 0; j < out_dim; ++j) ecoef += We[j] * a_edge[j];
    __syncthreads();
    for (int e = tid; e < N_ETOT; e += nt) {
        float a = S.as_[S.srcs[e]] + S.ad_[S.dsts[e]] + S.ea[e] * ecoef;
        S.alpha[e] = (a >= 0.f) ? a : SLOPE * a;
    }
    __syncthreads();
    for (int d = tid; d < N_NODES; d += nt) {
        float m = -INFINITY;
        for (int k = S.off[d]; k < S.off[d + 1]; ++k) m = fmaxf(m, S.alpha[S.csr[k]]);
        float den = 0.f;
        for (int k = S.off[d]; k < S.off[d + 1]; ++k) {
            int e = S.csr[k];
            float ex = expf(S.alpha[e] - m);
            S.alpha[e] = ex;
            den += ex;
        }
        S.den_[d] = den;
    }
    __syncthreads();
    for (int idx = tid; idx < N_NODES * out_dim; idx += nt) {
        int d = idx / out_dim, j = idx % out_dim;
        float s = 0.f;
        for (int k = S.off[d]; k < S.off[d + 1]; ++k) {
            int e = S.csr[k];
            s += S.alpha[e] * xl[(int)S.srcs[e] * out_dim + j];
        }
        outb[idx] = s / S.den_[d] + bias[j];
    }
    __syncthreads();
}

__device__ void bn_relu(GnnS& S, const float* v, float* dst, int n) {
    const int tid = threadIdx.x, nt = blockDim.x;
    float s = 0.f;
    for (int i = tid; i < n; i += nt) s += v[i];
    float tot;
    block_reduce_sum(s, S.red, &tot);
    float avg = tot / n;
    float s2 = 0.f;
    for (int i = tid; i < n; i += nt) { float d = v[i] - avg; s2 += d * d; }
    block_reduce_sum(s2, S.red, &tot);
    float stdv = sqrtf(tot / n);
    for (int i = tid; i < n; i += nt) dst[i] = fmaxf((v[i] - avg) / stdv, 0.f);
    __syncthreads();
}

__device__ void gnn_path(GnnS& S,
    const float* node_fea, const float* edge_fea, const int* eidx,
    const float* g1w, const float* g1as, const float* g1ad,
    const float* g1we, const float* g1ae, const float* g1b,
    const float* g2w, const float* g2as, const float* g2ad,
    const float* g2we, const float* g2ae, const float* g2b,
    const float* fc1w, const float* fc1b, float* gcontrib) {
    const int tid = threadIdx.x, nt = blockDim.x;
    float s = 0.f;
    for (int e = tid; e < N_EDGES; e += nt) s += edge_fea[e];
    float tot;
    block_reduce_sum(s, S.red, &tot);
    float emean = tot / N_EDGES;
    for (int e = tid; e < N_ETOT; e += nt) {
        if (e < N_EDGES) {
            S.ea[e] = edge_fea[e];
            S.srcs[e] = (unsigned char)eidx[e];
            S.dsts[e] = (unsigned char)eidx[N_EDGES + e];
        } else {
            S.ea[e] = emean;
            S.srcs[e] = (unsigned char)(e - N_EDGES);
            S.dsts[e] = (unsigned char)(e - N_EDGES);
        }
    }
    if (tid < N_NODES) S.x_in[tid] = node_fea[tid];
    __syncthreads();
    if (tid < N_NODES) {
        int c = 0;
        for (int e = 0; e < N_ETOT; ++e) c += (S.dsts[e] == tid);
        S.cnt[tid] = c;
    }
    __syncthreads();
    if (tid == 0) {
        S.off[0] = 0;
        for (int d = 0; d < N_NODES; ++d) S.off[d + 1] = S.off[d] + S.cnt[d];
    }
    __syncthreads();
    if (tid < N_NODES) {
        int k = S.off[tid];
        for (int e = 0; e < N_ETOT; ++e)
            if (S.dsts[e] == tid) S.csr[k++] = (unsigned short)e;
    }
    __syncthreads();

    gat_layer(S, S.x_in, 1, 6, g1w, g1as, g1ad, g1we, g1ae, g1b, S.xl, S.outb);
    bn_relu(S, S.outb, S.x_in, N_NODES * 6);
    gat_layer(S, S.x_in, 6, 16, g2w, g2as, g2ad, g2we, g2ae, g2b, S.xl, S.outb);
    bn_relu(S, S.outb, S.x_in, N_NODES * 16);   // x_in[0..959] == g

    for (int j = tid; j < 512; j += nt) {
        float acc = fc1b[j];
#pragma unroll 4
        for (int k = 0; k < 960; ++k) acc += S.x_in[k] * fc1w[(size_t)k * 512 + j];
        gcontrib[j] = acc;
    }
}

// ---------------------------------------------------------------------------
// conv path. Block = 256 threads = 4 waves, 2 images.
// Lane-consecutive LDS addressing everywhere; weights via uniform scalar loads.
// relu(maxpool(x)) == maxpool(relu(x)).
// ---------------------------------------------------------------------------
__device__ void conv_path(ConvS& C, int img0,
                          const float* __restrict__ pic,
                          const float* __restrict__ w1, const float* __restrict__ b1,
                          const float* __restrict__ w2, const float* __restrict__ b2,
                          float* __restrict__ p) {
    const int tid = threadIdx.x;
    const int w = tid >> 6, lane = tid & 63;

    // stage 2 images (coalesced float4; LDS writes lane-consecutive => no conflict)
    {
        const float4* src = (const float4*)(pic + (size_t)img0 * 3072);
        float4* dst = (float4*)C.simg;
        for (int i = tid; i < 1536; i += 256) dst[i] = src[i];
    }
    __syncthreads();

    // ---------------- conv1: [3,32,32] -> pool -> c1[6,14,16] ----------------
    // wave w: img = w>>1, handles ypairs {half, half+2, ..., half+12}, half = w&1
    {
        const int img = w >> 1, half = w & 1;
        const int y_rel = lane >> 5, x = lane & 31;
        const float* S = C.simg + img * 3072;
        float acc[7][6];
#pragma unroll
        for (int j = 0; j < 7; ++j)
#pragma unroll
            for (int oc = 0; oc < 6; ++oc) acc[j][oc] = b1[oc];

        for (int ic = 0; ic < 3; ++ic)
            for (int ky = 0; ky < 5; ++ky) {
                float wv[6][5];
#pragma unroll
                for (int oc = 0; oc < 6; ++oc)
#pragma unroll
                    for (int kx = 0; kx < 5; ++kx)
                        wv[oc][kx] = w1[(oc * 3 + ic) * 25 + ky * 5 + kx];
                const float* Sc = S + ic * 1024 + x;
#pragma unroll
                for (int j = 0; j < 7; ++j) {
                    int row = 2 * (half + 2 * j) + y_rel + ky;   // <= 31
                    const float* rp = Sc + row * 32;
                    float v0 = rp[0], v1 = rp[1], v2 = rp[2], v3 = rp[3], v4 = rp[4];
#pragma unroll
                    for (int oc = 0; oc < 6; ++oc)
                        acc[j][oc] += v0 * wv[oc][0] + v1 * wv[oc][1] + v2 * wv[oc][2]
                                    + v3 * wv[oc][3] + v4 * wv[oc][4];
                }
            }
        // pool 2x2 (x-pair via xor1, y-pair via xor32) + relu, write c1
#pragma unroll
        for (int j = 0; j < 7; ++j) {
            int yp = half + 2 * j;
#pragma unroll
            for (int oc = 0; oc < 6; ++oc) {
                float v = acc[j][oc];
                v = fmaxf(v, __shfl_xor(v, 1, 64));
                v = fmaxf(v, __shfl_xor(v, 32, 64));
                v = fmaxf(v, 0.f);
                if (y_rel == 0 && (x & 1) == 0 && x < 28)
                    C.c1[((img * 6 + oc) * 14 + yp) * 16 + (x >> 1)] = v;
            }
        }
    }
    __syncthreads();

    // ---------------- conv2: c1[6,14,16] -> pool -> p[16,5,5] ----------------
    // wave w: img = w>>1, oc-half = w&1; 3 row-tasks (conv rows 4t..4t+3)
    {
        const int img = w >> 1, och = w & 1;
        const int y_rel = lane >> 4, x = lane & 15;
        const float* C1 = C.c1 + img * (6 * 14 * 16);
        float acc[3][8];
#pragma unroll
        for (int t = 0; t < 3; ++t)
#pragma unroll
            for (int o = 0; o < 8; ++o) acc[t][o] = b2[och * 8 + o];

        for (int ic = 0; ic < 6; ++ic)
            for (int ky = 0; ky < 5; ++ky) {
                float wv[8][5];
#pragma unroll
                for (int o = 0; o < 8; ++o)
#pragma unroll
                    for (int kx = 0; kx < 5; ++kx)
                        wv[o][kx] = w2[((och * 8 + o) * 6 + ic) * 25 + ky * 5 + kx];
                const float* Cc = C1 + ic * 224 + x;
#pragma unroll
                for (int t = 0; t < 3; ++t) {
                    int row = 4 * t + y_rel + ky;
                    row = (row < 14) ? row : 13;                 // clamp garbage lanes
                    const float* rp = Cc + row * 16;
                    float v0 = rp[0], v1 = rp[1], v2 = rp[2], v3 = rp[3], v4 = rp[4];
#pragma unroll
                    for (int o = 0; o < 8; ++o)
                        acc[t][o] += v0 * wv[o][0] + v1 * wv[o][1] + v2 * wv[o][2]
                                   + v3 * wv[o][3] + v4 * wv[o][4];
                }
            }
        // pool 2x2 (x-pair xor1, y-pair xor16) + relu, write p (global)
#pragma unroll
        for (int t = 0; t < 3; ++t) {
#pragma unroll
            for (int o = 0; o < 8; ++o) {
                float v = acc[t][o];
                v = fmaxf(v, __shfl_xor(v, 1, 64));
                v = fmaxf(v, __shfl_xor(v, 16, 64));
                v = fmaxf(v, 0.f);
                int py = 2 * t + (y_rel >> 1);
                if ((y_rel & 1) == 0 && (x & 1) == 0 && x < 10 && py < 5) {
                    int oc = och * 8 + o;
                    p[((size_t)(img0 + img) * 16 + oc) * 25 + py * 5 + (x >> 1)] = v;
                }
            }
        }
    }
}

__global__ void __launch_bounds__(256, 4) fused_kernel(
    const float* __restrict__ node_fea, const float* __restrict__ edge_fea,
    const int* __restrict__ eidx,
    const float* g1w, const float* g1as, const float* g1ad,
    const float* g1we, const float* g1ae, const float* g1b,
    const float* g2w, const float* g2as, const float* g2ad,
    const float* g2we, const float* g2ae, const float* g2b,
    const float* __restrict__ fc1w, const float* __restrict__ fc1b,
    float* __restrict__ gcontrib,
    const float* __restrict__ pic,
    const float* __restrict__ c1w, const float* __restrict__ c1b,
    const float* __restrict__ c2w, const float* __restrict__ c2b,
    float* __restrict__ p) {
    __shared__ SMem u;
    if (blockIdx.x == 0) {
        gnn_path(u.g, node_fea, edge_fea, eidx,
                 g1w, g1as, g1ad, g1we, g1ae, g1b,
                 g2w, g2as, g2ad, g2we, g2ae, g2b,
                 fc1w, fc1b, gcontrib);
    } else {
        conv_path(u.c, (blockIdx.x - 1) * 2, pic, c1w, c1b, c2w, c2b, p);
    }
}

// ---------------------------------------------------------------------------
// FC1: h[b,j] = relu(gcontrib[j] + sum_k p[b,k]*w2[k,j]); w2 = fc1_w[960:,:]
// ---------------------------------------------------------------------------
#define FC1_ROWS 16
__global__ void __launch_bounds__(256) fc1_kernel(
    const float* __restrict__ p, const float* __restrict__ w,
    const float* __restrict__ gcontrib, float* __restrict__ h) {
    __shared__ float sp[FC1_ROWS * 400];
    const int tid = threadIdx.x;
    const size_t r0 = (size_t)blockIdx.x * FC1_ROWS;
    for (int i = tid; i < FC1_ROWS * 400; i += 256) sp[i] = p[r0 * 400 + i];
    __syncthreads();
    const int c0 = tid, c1 = tid + 256;
    float acc[FC1_ROWS][2];
#pragma unroll
    for (int r = 0; r < FC1_ROWS; ++r) { acc[r][0] = 0.f; acc[r][1] = 0.f; }
    for (int k = 0; k < 400; k += 4) {
        float wa0 = w[(size_t)(k + 0) * 512 + c0], wa1 = w[(size_t)(k + 0) * 512 + c1];
        float wb0 = w[(size_t)(k + 1) * 512 + c0], wb1 = w[(size_t)(k + 1) * 512 + c1];
        float wc0 = w[(size_t)(k + 2) * 512 + c0], wc1 = w[(size_t)(k + 2) * 512 + c1];
        float wd0 = w[(size_t)(k + 3) * 512 + c0], wd1 = w[(size_t)(k + 3) * 512 + c1];
#pragma unroll
        for (int r = 0; r < FC1_ROWS; ++r) {
            float4 pv = *(const float4*)&sp[r * 400 + k];
            acc[r][0] += pv.x * wa0 + pv.y * wb0 + pv.z * wc0 + pv.w * wd0;
            acc[r][1] += pv.x * wa1 + pv.y * wb1 + pv.z * wc1 + pv.w * wd1;
        }
    }
    float g0 = gcontrib[c0], g1 = gcontrib[c1];
#pragma unroll
    for (int r = 0; r < FC1_ROWS; ++r) {
        h[(r0 + r) * 512 + c0] = fmaxf(acc[r][0] + g0, 0.f);
        h[(r0 + r) * 512 + c1] = fmaxf(acc[r][1] + g1, 0.f);
    }
}

// ---------------------------------------------------------------------------
// FC2: out[b,j] = tanh(sum_k h[b,k]*fc2_w[k,j] + fc2_b[j]); one wave per row
// ---------------------------------------------------------------------------
__global__ void __launch_bounds__(256) fc2_kernel(
    const float* __restrict__ h, const float* __restrict__ w,
    const float* __restrict__ b, float* __restrict__ out) {
    const int wave = threadIdx.x >> 6, lane = threadIdx.x & 63;
    const size_t row = (size_t)blockIdx.x * 4 + wave;
    const float* hr = h + row * 512;
    float partial[10];
#pragma unroll
    for (int j = 0; j < 10; ++j) partial[j] = 0.f;
    for (int k = lane; k < 512; k += 64) {
        float hv = hr[k];
        const float* wr = w + (size_t)k * 10;
#pragma unroll
        for (int j = 0; j < 10; ++j) partial[j] += hv * wr[j];
    }
#pragma unroll
    for (int j = 0; j < 10; ++j) {
        float v = partial[j];
        for (int sft = 32; sft > 0; sft >>= 1) v += __shfl_xor(v, sft, 64);
        partial[j] = v;
    }
    if (lane == 0) {
#pragma unroll
        for (int j = 0; j < 10; ++j)
            out[row * 10 + j] = tanhf(partial[j] + b[j]);
    }
}

extern "C" void kernel_launch(void* const* d_in, const int* in_sizes, int n_in,
                              void* d_out, int out_size, void* d_ws, size_t ws_size,
                              hipStream_t stream) {
    const float* node_fea = (const float*)d_in[0];
    const float* edge_fea = (const float*)d_in[1];
    const float* pic      = (const float*)d_in[2];
    const float* c1w = (const float*)d_in[3];
    const float* c1b = (const float*)d_in[4];
    const float* c2w = (const float*)d_in[5];
    const float* c2b = (const float*)d_in[6];
    const float* g1w  = (const float*)d_in[7];
    const float* g1as = (const float*)d_in[8];
    const float* g1ad = (const float*)d_in[9];
    const float* g1we = (const float*)d_in[10];
    const float* g1ae = (const float*)d_in[11];
    const float* g1b  = (const float*)d_in[12];
    const float* g2w  = (const float*)d_in[13];
    const float* g2as = (const float*)d_in[14];
    const float* g2ad = (const float*)d_in[15];
    const float* g2we = (const float*)d_in[16];
    const float* g2ae = (const float*)d_in[17];
    const float* g2b  = (const float*)d_in[18];
    const float* fc1w = (const float*)d_in[19];
    const float* fc1b = (const float*)d_in[20];
    const float* fc2w = (const float*)d_in[21];
    const float* fc2b = (const float*)d_in[22];
    const int*   eidx = (const int*)d_in[23];
    float* out = (float*)d_out;

    char* ws = (char*)d_ws;
    float* gcontrib = (float*)ws;                                   // 512 f
    float* p = (float*)(ws + 2048);                                 // 8192*400 f
    float* h = (float*)(ws + 2048 + (size_t)8192 * 400 * 4);        // 8192*512 f

    hipLaunchKernelGGL(fused_kernel, dim3(4097), dim3(256), 0, stream,
                       node_fea, edge_fea, eidx,
                       g1w, g1as, g1ad, g1we, g1ae, g1b,
                       g2w, g2as, g2ad, g2we, g2ae, g2b,
                       fc1w, fc1b, gcontrib,
                       pic, c1w, c1b, c2w, c2b, p);
    hipLaunchKernelGGL(fc1_kernel, dim3(8192 / FC1_ROWS), dim3(256), 0, stream,
                       p, fc1w + (size_t)960 * 512, gcontrib, h);
    hipLaunchKernelGGL(fc2_kernel, dim3(8192 / 4), dim3(256), 0, stream,
                       h, fc2w, fc2b, out);
}

// Round 4
// 2157.407 us; speedup vs baseline: 1.8741x; 1.8741x over previous
//
#include <hip/hip_runtime.h>
#include <math.h>

#define N_NODES 60
#define N_EDGES 1800
#define N_ETOT  1860
#define SLOPE   0.2f

// ---------------- LDS union: conv path vs gnn path (block 0) ----------------
// conv layout: simg[2 img][3 ic][32 y][32 x]  (6144 f)
//              c1  [2 img][6 ic][14 y][16 x]  (2688 f, x padded 14->16)
struct ConvS {
    float simg[2 * 3 * 32 * 32];
    float c1[2 * 6 * 14 * 16];
    float pad[16];               // absorbs halo over-reads
};
struct GnnS {
    float ea[N_ETOT];
    float alpha[N_ETOT];         // becomes exp() in place
    float x_in[960];
    float xl[960];
    float outb[960];
    float as_[N_NODES], ad_[N_NODES], den_[N_NODES];
    float red[256];
    unsigned char srcs[N_ETOT], dsts[N_ETOT];
    unsigned short csr[N_ETOT];
    int cnt[N_NODES], off[N_NODES + 4];
};
union SMem { ConvS c; GnnS g; };

__device__ __forceinline__ void block_reduce_sum(float v, float* red, float* out) {
    int tid = threadIdx.x;
    red[tid] = v;
    __syncthreads();
    for (int st = 128; st > 0; st >>= 1) {
        if (tid < st) red[tid] += red[tid + st];
        __syncthreads();
    }
    *out = red[0];
    __syncthreads();
}

__device__ void gat_layer(GnnS& S, const float* x_in, int in_dim, int out_dim,
                          const float* W, const float* a_src, const float* a_dst,
                          const float* We, const float* a_edge, const float* bias,
                          float* xl, float* outb) {
    const int tid = threadIdx.x, nt = blockDim.x;
    for (int idx = tid; idx < N_NODES * out_dim; idx += nt) {
        int i = idx / out_dim, j = idx % out_dim;
        float s = 0.f;
        for (int k = 0; k < in_dim; ++k) s += x_in[i * in_dim + k] * W[k * out_dim + j];
        xl[idx] = s;
    }
    __syncthreads();
    for (int i = tid; i < N_NODES; i += nt) {
        float s = 0.f, d = 0.f;
        for (int j = 0; j < out_dim; ++j) {
            s += xl[i * out_dim + j] * a_src[j];
            d += xl[i * out_dim + j] * a_dst[j];
        }
        S.as_[i] = s; S.ad_[i] = d;
    }
    float ecoef = 0.f;
    for (int j = 0; j < out_dim; ++j) ecoef += We[j] * a_edge[j];
    __syncthreads();
    for (int e = tid; e < N_ETOT; e += nt) {
        float a = S.as_[S.srcs[e]] + S.ad_[S.dsts[e]] + S.ea[e] * ecoef;
        S.alpha[e] = (a >= 0.f) ? a : SLOPE * a;
    }
    __syncthreads();
    for (int d = tid; d < N_NODES; d += nt) {
        float m = -INFINITY;
        for (int k = S.off[d]; k < S.off[d + 1]; ++k) m = fmaxf(m, S.alpha[S.csr[k]]);
        float den = 0.f;
        for (int k = S.off[d]; k < S.off[d + 1]; ++k) {
            int e = S.csr[k];
            float ex = expf(S.alpha[e] - m);
            S.alpha[e] = ex;
            den += ex;
        }
        S.den_[d] = den;
    }
    __syncthreads();
    for (int idx = tid; idx < N_NODES * out_dim; idx += nt) {
        int d = idx / out_dim, j = idx % out_dim;
        float s = 0.f;
        for (int k = S.off[d]; k < S.off[d + 1]; ++k) {
            int e = S.csr[k];
            s += S.alpha[e] * xl[(int)S.srcs[e] * out_dim + j];
        }
        outb[idx] = s / S.den_[d] + bias[j];
    }
    __syncthreads();
}

__device__ void bn_relu(GnnS& S, const float* v, float* dst, int n) {
    const int tid = threadIdx.x, nt = blockDim.x;
    float s = 0.f;
    for (int i = tid; i < n; i += nt) s += v[i];
    float tot;
    block_reduce_sum(s, S.red, &tot);
    float avg = tot / n;
    float s2 = 0.f;
    for (int i = tid; i < n; i += nt) { float d = v[i] - avg; s2 += d * d; }
    block_reduce_sum(s2, S.red, &tot);
    float stdv = sqrtf(tot / n);
    for (int i = tid; i < n; i += nt) dst[i] = fmaxf((v[i] - avg) / stdv, 0.f);
    __syncthreads();
}

__device__ void gnn_path(GnnS& S,
    const float* node_fea, const float* edge_fea, const int* eidx,
    const float* g1w, const float* g1as, const float* g1ad,
    const float* g1we, const float* g1ae, const float* g1b,
    const float* g2w, const float* g2as, const float* g2ad,
    const float* g2we, const float* g2ae, const float* g2b,
    const float* fc1w, const float* fc1b, float* gcontrib) {
    const int tid = threadIdx.x, nt = blockDim.x;
    float s = 0.f;
    for (int e = tid; e < N_EDGES; e += nt) s += edge_fea[e];
    float tot;
    block_reduce_sum(s, S.red, &tot);
    float emean = tot / N_EDGES;
    for (int e = tid; e < N_ETOT; e += nt) {
        if (e < N_EDGES) {
            S.ea[e] = edge_fea[e];
            S.srcs[e] = (unsigned char)eidx[e];
            S.dsts[e] = (unsigned char)eidx[N_EDGES + e];
        } else {
            S.ea[e] = emean;
            S.srcs[e] = (unsigned char)(e - N_EDGES);
            S.dsts[e] = (unsigned char)(e - N_EDGES);
        }
    }
    if (tid < N_NODES) S.x_in[tid] = node_fea[tid];
    __syncthreads();
    if (tid < N_NODES) {
        int c = 0;
        for (int e = 0; e < N_ETOT; ++e) c += (S.dsts[e] == tid);
        S.cnt[tid] = c;
    }
    __syncthreads();
    if (tid == 0) {
        S.off[0] = 0;
        for (int d = 0; d < N_NODES; ++d) S.off[d + 1] = S.off[d] + S.cnt[d];
    }
    __syncthreads();
    if (tid < N_NODES) {
        int k = S.off[tid];
        for (int e = 0; e < N_ETOT; ++e)
            if (S.dsts[e] == tid) S.csr[k++] = (unsigned short)e;
    }
    __syncthreads();

    gat_layer(S, S.x_in, 1, 6, g1w, g1as, g1ad, g1we, g1ae, g1b, S.xl, S.outb);
    bn_relu(S, S.outb, S.x_in, N_NODES * 6);
    gat_layer(S, S.x_in, 6, 16, g2w, g2as, g2ad, g2we, g2ae, g2b, S.xl, S.outb);
    bn_relu(S, S.outb, S.x_in, N_NODES * 16);   // x_in[0..959] == g

    for (int j = tid; j < 512; j += nt) {
        float acc = fc1b[j];
#pragma unroll 4
        for (int k = 0; k < 960; ++k) acc += S.x_in[k] * fc1w[(size_t)k * 512 + j];
        gcontrib[j] = acc;
    }
}

// ---------------------------------------------------------------------------
// conv path. Block = 256 threads = 4 waves, 2 images.
// Lane-consecutive LDS addressing everywhere; weights via uniform scalar loads.
// relu(maxpool(x)) == maxpool(relu(x)).
// ---------------------------------------------------------------------------
__device__ void conv_path(ConvS& C, int img0,
                          const float* __restrict__ pic,
                          const float* __restrict__ w1, const float* __restrict__ b1,
                          const float* __restrict__ w2, const float* __restrict__ b2,
                          float* __restrict__ p) {
    const int tid = threadIdx.x;
    const int w = tid >> 6, lane = tid & 63;

    // stage 2 images (coalesced float4; LDS writes lane-consecutive => no conflict)
    {
        const float4* src = (const float4*)(pic + (size_t)img0 * 3072);
        float4* dst = (float4*)C.simg;
        for (int i = tid; i < 1536; i += 256) dst[i] = src[i];
    }
    __syncthreads();

    // ---------------- conv1: [3,32,32] -> pool -> c1[6,14,16] ----------------
    // wave w: img = w>>1, handles ypairs {half, half+2, ..., half+12}, half = w&1
    {
        const int img = w >> 1, half = w & 1;
        const int y_rel = lane >> 5, x = lane & 31;
        const float* S = C.simg + img * 3072;
        float acc[7][6];
#pragma unroll
        for (int j = 0; j < 7; ++j)
#pragma unroll
            for (int oc = 0; oc < 6; ++oc) acc[j][oc] = b1[oc];

        for (int ic = 0; ic < 3; ++ic)
            for (int ky = 0; ky < 5; ++ky) {
                float wv[6][5];
#pragma unroll
                for (int oc = 0; oc < 6; ++oc)
#pragma unroll
                    for (int kx = 0; kx < 5; ++kx)
                        wv[oc][kx] = w1[(oc * 3 + ic) * 25 + ky * 5 + kx];
                const float* Sc = S + ic * 1024 + x;
#pragma unroll
                for (int j = 0; j < 7; ++j) {
                    int row = 2 * (half + 2 * j) + y_rel + ky;   // <= 31
                    const float* rp = Sc + row * 32;
                    float v0 = rp[0], v1 = rp[1], v2 = rp[2], v3 = rp[3], v4 = rp[4];
#pragma unroll
                    for (int oc = 0; oc < 6; ++oc)
                        acc[j][oc] += v0 * wv[oc][0] + v1 * wv[oc][1] + v2 * wv[oc][2]
                                    + v3 * wv[oc][3] + v4 * wv[oc][4];
                }
            }
        // pool 2x2 (x-pair via xor1, y-pair via xor32) + relu, write c1
#pragma unroll
        for (int j = 0; j < 7; ++j) {
            int yp = half + 2 * j;
#pragma unroll
            for (int oc = 0; oc < 6; ++oc) {
                float v = acc[j][oc];
                v = fmaxf(v, __shfl_xor(v, 1, 64));
                v = fmaxf(v, __shfl_xor(v, 32, 64));
                v = fmaxf(v, 0.f);
                if (y_rel == 0 && (x & 1) == 0 && x < 28)
                    C.c1[((img * 6 + oc) * 14 + yp) * 16 + (x >> 1)] = v;
            }
        }
    }
    __syncthreads();

    // ---------------- conv2: c1[6,14,16] -> pool -> p[16,5,5] ----------------
    // wave w: img = w>>1, oc-half = w&1; 3 row-tasks (conv rows 4t..4t+3)
    {
        const int img = w >> 1, och = w & 1;
        const int y_rel = lane >> 4, x = lane & 15;
        const float* C1 = C.c1 + img * (6 * 14 * 16);
        float acc[3][8];
#pragma unroll
        for (int t = 0; t < 3; ++t)
#pragma unroll
            for (int o = 0; o < 8; ++o) acc[t][o] = b2[och * 8 + o];

        for (int ic = 0; ic < 6; ++ic)
            for (int ky = 0; ky < 5; ++ky) {
                float wv[8][5];
#pragma unroll
                for (int o = 0; o < 8; ++o)
#pragma unroll
                    for (int kx = 0; kx < 5; ++kx)
                        wv[o][kx] = w2[((och * 8 + o) * 6 + ic) * 25 + ky * 5 + kx];
                const float* Cc = C1 + ic * 224 + x;
#pragma unroll
                for (int t = 0; t < 3; ++t) {
                    int row = 4 * t + y_rel + ky;
                    row = (row < 14) ? row : 13;                 // clamp garbage lanes
                    const float* rp = Cc + row * 16;
                    float v0 = rp[0], v1 = rp[1], v2 = rp[2], v3 = rp[3], v4 = rp[4];
#pragma unroll
                    for (int o = 0; o < 8; ++o)
                        acc[t][o] += v0 * wv[o][0] + v1 * wv[o][1] + v2 * wv[o][2]
                                   + v3 * wv[o][3] + v4 * wv[o][4];
                }
            }
        // pool 2x2 (x-pair xor1, y-pair xor16) + relu, write p (global)
#pragma unroll
        for (int t = 0; t < 3; ++t) {
#pragma unroll
            for (int o = 0; o < 8; ++o) {
                float v = acc[t][o];
                v = fmaxf(v, __shfl_xor(v, 1, 64));
                v = fmaxf(v, __shfl_xor(v, 16, 64));
                v = fmaxf(v, 0.f);
                int py = 2 * t + (y_rel >> 1);
                if ((y_rel & 1) == 0 && (x & 1) == 0 && x < 10 && py < 5) {
                    int oc = och * 8 + o;
                    p[((size_t)(img0 + img) * 16 + oc) * 25 + py * 5 + (x >> 1)] = v;
                }
            }
        }
    }
}

__global__ void __launch_bounds__(256, 2) fused_kernel(
    const float* __restrict__ node_fea, const float* __restrict__ edge_fea,
    const int* __restrict__ eidx,
    const float* g1w, const float* g1as, const float* g1ad,
    const float* g1we, const float* g1ae, const float* g1b,
    const float* g2w, const float* g2as, const float* g2ad,
    const float* g2we, const float* g2ae, const float* g2b,
    const float* __restrict__ fc1w, const float* __restrict__ fc1b,
    float* __restrict__ gcontrib,
    const float* __restrict__ pic,
    const float* __restrict__ c1w, const float* __restrict__ c1b,
    const float* __restrict__ c2w, const float* __restrict__ c2b,
    float* __restrict__ p) {
    __shared__ SMem u;
    if (blockIdx.x == 0) {
        gnn_path(u.g, node_fea, edge_fea, eidx,
                 g1w, g1as, g1ad, g1we, g1ae, g1b,
                 g2w, g2as, g2ad, g2we, g2ae, g2b,
                 fc1w, fc1b, gcontrib);
    } else {
        conv_path(u.c, (blockIdx.x - 1) * 2, pic, c1w, c1b, c2w, c2b, p);
    }
}

// ---------------------------------------------------------------------------
// FC1: h[b,j] = relu(gcontrib[j] + sum_k p[b,k]*w2[k,j]); w2 = fc1_w[960:,:]
// ---------------------------------------------------------------------------
#define FC1_ROWS 16
__global__ void fc1_kernel(
    const float* __restrict__ p, const float* __restrict__ w,
    const float* __restrict__ gcontrib, float* __restrict__ h) {
    __shared__ float sp[FC1_ROWS * 400];
    const int tid = threadIdx.x;
    const size_t r0 = (size_t)blockIdx.x * FC1_ROWS;
    for (int i = tid; i < FC1_ROWS * 400; i += 256) sp[i] = p[r0 * 400 + i];
    __syncthreads();
    const int c0 = tid, c1 = tid + 256;
    float acc[FC1_ROWS][2];
#pragma unroll
    for (int r = 0; r < FC1_ROWS; ++r) { acc[r][0] = 0.f; acc[r][1] = 0.f; }
    for (int k = 0; k < 400; k += 4) {
        float wa0 = w[(size_t)(k + 0) * 512 + c0], wa1 = w[(size_t)(k + 0) * 512 + c1];
        float wb0 = w[(size_t)(k + 1) * 512 + c0], wb1 = w[(size_t)(k + 1) * 512 + c1];
        float wc0 = w[(size_t)(k + 2) * 512 + c0], wc1 = w[(size_t)(k + 2) * 512 + c1];
        float wd0 = w[(size_t)(k + 3) * 512 + c0], wd1 = w[(size_t)(k + 3) * 512 + c1];
#pragma unroll
        for (int r = 0; r < FC1_ROWS; ++r) {
            float4 pv = *(const float4*)&sp[r * 400 + k];
            acc[r][0] += pv.x * wa0 + pv.y * wb0 + pv.z * wc0 + pv.w * wd0;
            acc[r][1] += pv.x * wa1 + pv.y * wb1 + pv.z * wc1 + pv.w * wd1;
        }
    }
    float g0 = gcontrib[c0], g1 = gcontrib[c1];
#pragma unroll
    for (int r = 0; r < FC1_ROWS; ++r) {
        h[(r0 + r) * 512 + c0] = fmaxf(acc[r][0] + g0, 0.f);
        h[(r0 + r) * 512 + c1] = fmaxf(acc[r][1] + g1, 0.f);
    }
}

// ---------------------------------------------------------------------------
// FC2: out[b,j] = tanh(sum_k h[b,k]*fc2_w[k,j] + fc2_b[j]); one wave per row
// ---------------------------------------------------------------------------
__global__ void fc2_kernel(
    const float* __restrict__ h, const float* __restrict__ w,
    const float* __restrict__ b, float* __restrict__ out) {
    const int wave = threadIdx.x >> 6, lane = threadIdx.x & 63;
    const size_t row = (size_t)blockIdx.x * 4 + wave;
    const float* hr = h + row * 512;
    float partial[10];
#pragma unroll
    for (int j = 0; j < 10; ++j) partial[j] = 0.f;
    for (int k = lane; k < 512; k += 64) {
        float hv = hr[k];
        const float* wr = w + (size_t)k * 10;
#pragma unroll
        for (int j = 0; j < 10; ++j) partial[j] += hv * wr[j];
    }
#pragma unroll
    for (int j = 0; j < 10; ++j) {
        float v = partial[j];
        for (int sft = 32; sft > 0; sft >>= 1) v += __shfl_xor(v, sft, 64);
        partial[j] = v;
    }
    if (lane == 0) {
#pragma unroll
        for (int j = 0; j < 10; ++j)
            out[row * 10 + j] = tanhf(partial[j] + b[j]);
    }
}

extern "C" void kernel_launch(void* const* d_in, const int* in_sizes, int n_in,
                              void* d_out, int out_size, void* d_ws, size_t ws_size,
                              hipStream_t stream) {
    const float* node_fea = (const float*)d_in[0];
    const float* edge_fea = (const float*)d_in[1];
    const float* pic      = (const float*)d_in[2];
    const float* c1w = (const float*)d_in[3];
    const float* c1b = (const float*)d_in[4];
    const float* c2w = (const float*)d_in[5];
    const float* c2b = (const float*)d_in[6];
    const float* g1w  = (const float*)d_in[7];
    const float* g1as = (const float*)d_in[8];
    const float* g1ad = (const float*)d_in[9];
    const float* g1we = (const float*)d_in[10];
    const float* g1ae = (const float*)d_in[11];
    const float* g1b  = (const float*)d_in[12];
    const float* g2w  = (const float*)d_in[13];
    const float* g2as = (const float*)d_in[14];
    const float* g2ad = (const float*)d_in[15];
    const float* g2we = (const float*)d_in[16];
    const float* g2ae = (const float*)d_in[17];
    const float* g2b  = (const float*)d_in[18];
    const float* fc1w = (const float*)d_in[19];
    const float* fc1b = (const float*)d_in[20];
    const float* fc2w = (const float*)d_in[21];
    const float* fc2b = (const float*)d_in[22];
    const int*   eidx = (const int*)d_in[23];
    float* out = (float*)d_out;

    char* ws = (char*)d_ws;
    float* gcontrib = (float*)ws;                                   // 512 f
    float* p = (float*)(ws + 2048);                                 // 8192*400 f
    float* h = (float*)(ws + 2048 + (size_t)8192 * 400 * 4);        // 8192*512 f

    hipLaunchKernelGGL(fused_kernel, dim3(4097), dim3(256), 0, stream,
                       node_fea, edge_fea, eidx,
                       g1w, g1as, g1ad, g1we, g1ae, g1b,
                       g2w, g2as, g2ad, g2we, g2ae, g2b,
                       fc1w, fc1b, gcontrib,
                       pic, c1w, c1b, c2w, c2b, p);
    hipLaunchKernelGGL(fc1_kernel, dim3(8192 / FC1_ROWS), dim3(256), 0, stream,
                       p, fc1w + (size_t)960 * 512, gcontrib, h);
    hipLaunchKernelGGL(fc2_kernel, dim3(8192 / 4), dim3(256), 0, stream,
                       h, fc2w, fc2b, out);
}

// Round 7
// 877.127 us; speedup vs baseline: 4.6097x; 2.4596x over previous
//
#include <hip/hip_runtime.h>
#include <math.h>

#define N_NODES 60
#define N_EDGES 1800
#define N_ETOT  1860
#define SLOPE   0.2f

// ---------------- LDS union: conv path vs gnn path (block 0) ----------------
// conv layout: simg[2 img][3 ic][32 y][32 x]  (6144 f)
//              c1  [2 img][6 ic][14 y][16 x]  (2688 f, x padded 14->16)
struct ConvS {
    float simg[2 * 3 * 32 * 32];
    float c1[2 * 6 * 14 * 16];
    float pad[16];               // absorbs halo over-reads
};
struct GnnS {
    float ea[N_ETOT];
    float alpha[N_ETOT];         // becomes exp() in place
    float x_in[960];
    float xl[960];
    float outb[960];
    float as_[N_NODES], ad_[N_NODES], den_[N_NODES];
    float red[256];
    unsigned char srcs[N_ETOT], dsts[N_ETOT];
    unsigned short csr[N_ETOT];
    int cnt[N_NODES], off[N_NODES + 4];
};
union SMem { ConvS c; GnnS g; };

__device__ __forceinline__ void block_reduce_sum(float v, float* red, float* out) {
    int tid = threadIdx.x;
    red[tid] = v;
    __syncthreads();
    for (int st = 128; st > 0; st >>= 1) {
        if (tid < st) red[tid] += red[tid + st];
        __syncthreads();
    }
    *out = red[0];
    __syncthreads();
}

__device__ void gat_layer(GnnS& S, const float* x_in, int in_dim, int out_dim,
                          const float* W, const float* a_src, const float* a_dst,
                          const float* We, const float* a_edge, const float* bias,
                          float* xl, float* outb) {
    const int tid = threadIdx.x, nt = blockDim.x;
    for (int idx = tid; idx < N_NODES * out_dim; idx += nt) {
        int i = idx / out_dim, j = idx % out_dim;
        float s = 0.f;
        for (int k = 0; k < in_dim; ++k) s += x_in[i * in_dim + k] * W[k * out_dim + j];
        xl[idx] = s;
    }
    __syncthreads();
    for (int i = tid; i < N_NODES; i += nt) {
        float s = 0.f, d = 0.f;
        for (int j = 0; j < out_dim; ++j) {
            s += xl[i * out_dim + j] * a_src[j];
            d += xl[i * out_dim + j] * a_dst[j];
        }
        S.as_[i] = s; S.ad_[i] = d;
    }
    float ecoef = 0.f;
    for (int j = 0; j < out_dim; ++j) ecoef += We[j] * a_edge[j];
    __syncthreads();
    for (int e = tid; e < N_ETOT; e += nt) {
        float a = S.as_[S.srcs[e]] + S.ad_[S.dsts[e]] + S.ea[e] * ecoef;
        S.alpha[e] = (a >= 0.f) ? a : SLOPE * a;
    }
    __syncthreads();
    for (int d = tid; d < N_NODES; d += nt) {
        float m = -INFINITY;
        for (int k = S.off[d]; k < S.off[d + 1]; ++k) m = fmaxf(m, S.alpha[S.csr[k]]);
        float den = 0.f;
        for (int k = S.off[d]; k < S.off[d + 1]; ++k) {
            int e = S.csr[k];
            float ex = expf(S.alpha[e] - m);
            S.alpha[e] = ex;
            den += ex;
        }
        S.den_[d] = den;
    }
    __syncthreads();
    for (int idx = tid; idx < N_NODES * out_dim; idx += nt) {
        int d = idx / out_dim, j = idx % out_dim;
        float s = 0.f;
        for (int k = S.off[d]; k < S.off[d + 1]; ++k) {
            int e = S.csr[k];
            s += S.alpha[e] * xl[(int)S.srcs[e] * out_dim + j];
        }
        outb[idx] = s / S.den_[d] + bias[j];
    }
    __syncthreads();
}

__device__ void bn_relu(GnnS& S, const float* v, float* dst, int n) {
    const int tid = threadIdx.x, nt = blockDim.x;
    float s = 0.f;
    for (int i = tid; i < n; i += nt) s += v[i];
    float tot;
    block_reduce_sum(s, S.red, &tot);
    float avg = tot / n;
    float s2 = 0.f;
    for (int i = tid; i < n; i += nt) { float d = v[i] - avg; s2 += d * d; }
    block_reduce_sum(s2, S.red, &tot);
    float stdv = sqrtf(tot / n);
    for (int i = tid; i < n; i += nt) dst[i] = fmaxf((v[i] - avg) / stdv, 0.f);
    __syncthreads();
}

__device__ void gnn_path(GnnS& S,
    const float* node_fea, const float* edge_fea, const int* eidx,
    const float* g1w, const float* g1as, const float* g1ad,
    const float* g1we, const float* g1ae, const float* g1b,
    const float* g2w, const float* g2as, const float* g2ad,
    const float* g2we, const float* g2ae, const float* g2b,
    const float* fc1w, const float* fc1b, float* gcontrib) {
    const int tid = threadIdx.x, nt = blockDim.x;
    float s = 0.f;
    for (int e = tid; e < N_EDGES; e += nt) s += edge_fea[e];
    float tot;
    block_reduce_sum(s, S.red, &tot);
    float emean = tot / N_EDGES;
    for (int e = tid; e < N_ETOT; e += nt) {
        if (e < N_EDGES) {
            S.ea[e] = edge_fea[e];
            S.srcs[e] = (unsigned char)eidx[e];
            S.dsts[e] = (unsigned char)eidx[N_EDGES + e];
        } else {
            S.ea[e] = emean;
            S.srcs[e] = (unsigned char)(e - N_EDGES);
            S.dsts[e] = (unsigned char)(e - N_EDGES);
        }
    }
    if (tid < N_NODES) S.x_in[tid] = node_fea[tid];
    __syncthreads();
    if (tid < N_NODES) {
        int c = 0;
        for (int e = 0; e < N_ETOT; ++e) c += (S.dsts[e] == tid);
        S.cnt[tid] = c;
    }
    __syncthreads();
    if (tid == 0) {
        S.off[0] = 0;
        for (int d = 0; d < N_NODES; ++d) S.off[d + 1] = S.off[d] + S.cnt[d];
    }
    __syncthreads();
    if (tid < N_NODES) {
        int k = S.off[tid];
        for (int e = 0; e < N_ETOT; ++e)
            if (S.dsts[e] == tid) S.csr[k++] = (unsigned short)e;
    }
    __syncthreads();

    gat_layer(S, S.x_in, 1, 6, g1w, g1as, g1ad, g1we, g1ae, g1b, S.xl, S.outb);
    bn_relu(S, S.outb, S.x_in, N_NODES * 6);
    gat_layer(S, S.x_in, 6, 16, g2w, g2as, g2ad, g2we, g2ae, g2b, S.xl, S.outb);
    bn_relu(S, S.outb, S.x_in, N_NODES * 16);   // x_in[0..959] == g

    for (int j = tid; j < 512; j += nt) {
        float acc = fc1b[j];
#pragma unroll 4
        for (int k = 0; k < 960; ++k) acc += S.x_in[k] * fc1w[(size_t)k * 512 + j];
        gcontrib[j] = acc;
    }
}

// ---------------------------------------------------------------------------
// conv path. Block = 256 threads = 4 waves, 2 images.
// Lane-consecutive LDS addressing everywhere (R3: conflicts ~0).
// unroll pragmas bound the live set so VGPR fits 128 (R4 spilled: full
// ic/ky unroll hoisted ~150 weight loads). relu(maxpool(x))==maxpool(relu(x)).
// ---------------------------------------------------------------------------
__device__ void conv_path(ConvS& C, int img0,
                          const float* __restrict__ pic,
                          const float* __restrict__ w1, const float* __restrict__ b1,
                          const float* __restrict__ w2, const float* __restrict__ b2,
                          float* __restrict__ p) {
    const int tid = threadIdx.x;
    const int w = tid >> 6, lane = tid & 63;

    // stage 2 images (coalesced float4; LDS writes lane-consecutive => no conflict)
    {
        const float4* src = (const float4*)(pic + (size_t)img0 * 3072);
        float4* dst = (float4*)C.simg;
        for (int i = tid; i < 1536; i += 256) dst[i] = src[i];
    }
    __syncthreads();

    // ---------------- conv1: [3,32,32] -> pool -> c1[6,14,16] ----------------
    // wave w: img = w>>1, handles ypairs {half, half+2, ..., half+12}, half = w&1
    {
        const int img = w >> 1, half = w & 1;
        const int y_rel = lane >> 5, x = lane & 31;
        const float* S = C.simg + img * 3072;
        float acc[7][6];
#pragma unroll
        for (int j = 0; j < 7; ++j)
#pragma unroll
            for (int oc = 0; oc < 6; ++oc) acc[j][oc] = b1[oc];

#pragma unroll 1
        for (int ic = 0; ic < 3; ++ic)
#pragma unroll 1
            for (int ky = 0; ky < 5; ++ky) {
                float wv[6][5];
#pragma unroll
                for (int oc = 0; oc < 6; ++oc)
#pragma unroll
                    for (int kx = 0; kx < 5; ++kx)
                        wv[oc][kx] = w1[(oc * 3 + ic) * 25 + ky * 5 + kx];
                const float* Sc = S + ic * 1024 + x;
#pragma unroll 2
                for (int j = 0; j < 7; ++j) {
                    int row = 2 * (half + 2 * j) + y_rel + ky;   // <= 31
                    const float* rp = Sc + row * 32;
                    float v0 = rp[0], v1 = rp[1], v2 = rp[2], v3 = rp[3], v4 = rp[4];
#pragma unroll
                    for (int oc = 0; oc < 6; ++oc)
                        acc[j][oc] += v0 * wv[oc][0] + v1 * wv[oc][1] + v2 * wv[oc][2]
                                    + v3 * wv[oc][3] + v4 * wv[oc][4];
                }
            }
        // pool 2x2 (x-pair via xor1, y-pair via xor32) + relu, write c1
#pragma unroll
        for (int j = 0; j < 7; ++j) {
            int yp = half + 2 * j;
#pragma unroll
            for (int oc = 0; oc < 6; ++oc) {
                float v = acc[j][oc];
                v = fmaxf(v, __shfl_xor(v, 1, 64));
                v = fmaxf(v, __shfl_xor(v, 32, 64));
                v = fmaxf(v, 0.f);
                if (y_rel == 0 && (x & 1) == 0 && x < 28)
                    C.c1[((img * 6 + oc) * 14 + yp) * 16 + (x >> 1)] = v;
            }
        }
    }
    __syncthreads();

    // ---------------- conv2: c1[6,14,16] -> pool -> p[16,5,5] ----------------
    // wave w: img = w>>1, oc-half = w&1; 3 row-tasks (conv rows 4t..4t+3)
    {
        const int img = w >> 1, och = w & 1;
        const int y_rel = lane >> 4, x = lane & 15;
        const float* C1 = C.c1 + img * (6 * 14 * 16);
        float acc[3][8];
#pragma unroll
        for (int t = 0; t < 3; ++t)
#pragma unroll
            for (int o = 0; o < 8; ++o) acc[t][o] = b2[och * 8 + o];

#pragma unroll 1
        for (int ic = 0; ic < 6; ++ic)
#pragma unroll 1
            for (int ky = 0; ky < 5; ++ky) {
                float wv[8][5];
#pragma unroll
                for (int o = 0; o < 8; ++o)
#pragma unroll
                    for (int kx = 0; kx < 5; ++kx)
                        wv[o][kx] = w2[((och * 8 + o) * 6 + ic) * 25 + ky * 5 + kx];
                const float* Cc = C1 + ic * 224 + x;
#pragma unroll 1
                for (int t = 0; t < 3; ++t) {
                    int row = 4 * t + y_rel + ky;
                    row = (row < 14) ? row : 13;                 // clamp garbage lanes
                    const float* rp = Cc + row * 16;
                    float v0 = rp[0], v1 = rp[1], v2 = rp[2], v3 = rp[3], v4 = rp[4];
#pragma unroll
                    for (int o = 0; o < 8; ++o)
                        acc[t][o] += v0 * wv[o][0] + v1 * wv[o][1] + v2 * wv[o][2]
                                   + v3 * wv[o][3] + v4 * wv[o][4];
                }
            }
        // pool 2x2 (x-pair xor1, y-pair xor16) + relu, write p (global)
#pragma unroll
        for (int t = 0; t < 3; ++t) {
#pragma unroll
            for (int o = 0; o < 8; ++o) {
                float v = acc[t][o];
                v = fmaxf(v, __shfl_xor(v, 1, 64));
                v = fmaxf(v, __shfl_xor(v, 16, 64));
                v = fmaxf(v, 0.f);
                int py = 2 * t + (y_rel >> 1);
                if ((y_rel & 1) == 0 && (x & 1) == 0 && x < 10 && py < 5) {
                    int oc = och * 8 + o;
                    p[((size_t)(img0 + img) * 16 + oc) * 25 + py * 5 + (x >> 1)] = v;
                }
            }
        }
    }
}

__global__ void __launch_bounds__(256, 2) fused_kernel(
    const float* __restrict__ node_fea, const float* __restrict__ edge_fea,
    const int* __restrict__ eidx,
    const float* g1w, const float* g1as, const float* g1ad,
    const float* g1we, const float* g1ae, const float* g1b,
    const float* g2w, const float* g2as, const float* g2ad,
    const float* g2we, const float* g2ae, const float* g2b,
    const float* __restrict__ fc1w, const float* __restrict__ fc1b,
    float* __restrict__ gcontrib,
    const float* __restrict__ pic,
    const float* __restrict__ c1w, const float* __restrict__ c1b,
    const float* __restrict__ c2w, const float* __restrict__ c2b,
    float* __restrict__ p) {
    __shared__ SMem u;
    if (blockIdx.x == 0) {
        gnn_path(u.g, node_fea, edge_fea, eidx,
                 g1w, g1as, g1ad, g1we, g1ae, g1b,
                 g2w, g2as, g2ad, g2we, g2ae, g2b,
                 fc1w, fc1b, gcontrib);
    } else {
        conv_path(u.c, (blockIdx.x - 1) * 2, pic, c1w, c1b, c2w, c2b, p);
    }
}

// ---------------------------------------------------------------------------
// FC1: h[b,j] = relu(gcontrib[j] + sum_k p[b,k]*w2[k,j]); w2 = fc1_w[960:,:]
// ---------------------------------------------------------------------------
#define FC1_ROWS 16
__global__ void fc1_kernel(
    const float* __restrict__ p, const float* __restrict__ w,
    const float* __restrict__ gcontrib, float* __restrict__ h) {
    __shared__ float sp[FC1_ROWS * 400];
    const int tid = threadIdx.x;
    const size_t r0 = (size_t)blockIdx.x * FC1_ROWS;
    for (int i = tid; i < FC1_ROWS * 400; i += 256) sp[i] = p[r0 * 400 + i];
    __syncthreads();
    const int c0 = tid, c1 = tid + 256;
    float acc[FC1_ROWS][2];
#pragma unroll
    for (int r = 0; r < FC1_ROWS; ++r) { acc[r][0] = 0.f; acc[r][1] = 0.f; }
    for (int k = 0; k < 400; k += 4) {
        float wa0 = w[(size_t)(k + 0) * 512 + c0], wa1 = w[(size_t)(k + 0) * 512 + c1];
        float wb0 = w[(size_t)(k + 1) * 512 + c0], wb1 = w[(size_t)(k + 1) * 512 + c1];
        float wc0 = w[(size_t)(k + 2) * 512 + c0], wc1 = w[(size_t)(k + 2) * 512 + c1];
        float wd0 = w[(size_t)(k + 3) * 512 + c0], wd1 = w[(size_t)(k + 3) * 512 + c1];
#pragma unroll
        for (int r = 0; r < FC1_ROWS; ++r) {
            float4 pv = *(const float4*)&sp[r * 400 + k];
            acc[r][0] += pv.x * wa0 + pv.y * wb0 + pv.z * wc0 + pv.w * wd0;
            acc[r][1] += pv.x * wa1 + pv.y * wb1 + pv.z * wc1 + pv.w * wd1;
        }
    }
    float g0 = gcontrib[c0], g1 = gcontrib[c1];
#pragma unroll
    for (int r = 0; r < FC1_ROWS; ++r) {
        h[(r0 + r) * 512 + c0] = fmaxf(acc[r][0] + g0, 0.f);
        h[(r0 + r) * 512 + c1] = fmaxf(acc[r][1] + g1, 0.f);
    }
}

// ---------------------------------------------------------------------------
// FC2: out[b,j] = tanh(sum_k h[b,k]*fc2_w[k,j] + fc2_b[j]); one wave per row
// ---------------------------------------------------------------------------
__global__ void fc2_kernel(
    const float* __restrict__ h, const float* __restrict__ w,
    const float* __restrict__ b, float* __restrict__ out) {
    const int wave = threadIdx.x >> 6, lane = threadIdx.x & 63;
    const size_t row = (size_t)blockIdx.x * 4 + wave;
    const float* hr = h + row * 512;
    float partial[10];
#pragma unroll
    for (int j = 0; j < 10; ++j) partial[j] = 0.f;
    for (int k = lane; k < 512; k += 64) {
        float hv = hr[k];
        const float* wr = w + (size_t)k * 10;
#pragma unroll
        for (int j = 0; j < 10; ++j) partial[j] += hv * wr[j];
    }
#pragma unroll
    for (int j = 0; j < 10; ++j) {
        float v = partial[j];
        for (int sft = 32; sft > 0; sft >>= 1) v += __shfl_xor(v, sft, 64);
        partial[j] = v;
    }
    if (lane == 0) {
#pragma unroll
        for (int j = 0; j < 10; ++j)
            out[row * 10 + j] = tanhf(partial[j] + b[j]);
    }
}

extern "C" void kernel_launch(void* const* d_in, const int* in_sizes, int n_in,
                              void* d_out, int out_size, void* d_ws, size_t ws_size,
                              hipStream_t stream) {
    const float* node_fea = (const float*)d_in[0];
    const float* edge_fea = (const float*)d_in[1];
    const float* pic      = (const float*)d_in[2];
    const float* c1w = (const float*)d_in[3];
    const float* c1b = (const float*)d_in[4];
    const float* c2w = (const float*)d_in[5];
    const float* c2b = (const float*)d_in[6];
    const float* g1w  = (const float*)d_in[7];
    const float* g1as = (const float*)d_in[8];
    const float* g1ad = (const float*)d_in[9];
    const float* g1we = (const float*)d_in[10];
    const float* g1ae = (const float*)d_in[11];
    const float* g1b  = (const float*)d_in[12];
    const float* g2w  = (const float*)d_in[13];
    const float* g2as = (const float*)d_in[14];
    const float* g2ad = (const float*)d_in[15];
    const float* g2we = (const float*)d_in[16];
    const float* g2ae = (const float*)d_in[17];
    const float* g2b  = (const float*)d_in[18];
    const float* fc1w = (const float*)d_in[19];
    const float* fc1b = (const float*)d_in[20];
    const float* fc2w = (const float*)d_in[21];
    const float* fc2b = (const float*)d_in[22];
    const int*   eidx = (const int*)d_in[23];
    float* out = (float*)d_out;

    char* ws = (char*)d_ws;
    float* gcontrib = (float*)ws;                                   // 512 f
    float* p = (float*)(ws + 2048);                                 // 8192*400 f
    float* h = (float*)(ws + 2048 + (size_t)8192 * 400 * 4);        // 8192*512 f

    hipLaunchKernelGGL(fused_kernel, dim3(4097), dim3(256), 0, stream,
                       node_fea, edge_fea, eidx,
                       g1w, g1as, g1ad, g1we, g1ae, g1b,
                       g2w, g2as, g2ad, g2we, g2ae, g2b,
                       fc1w, fc1b, gcontrib,
                       pic, c1w, c1b, c2w, c2b, p);
    hipLaunchKernelGGL(fc1_kernel, dim3(8192 / FC1_ROWS), dim3(256), 0, stream,
                       p, fc1w + (size_t)960 * 512, gcontrib, h);
    hipLaunchKernelGGL(fc2_kernel, dim3(8192 / 4), dim3(256), 0, stream,
                       h, fc2w, fc2b, out);
}

// Round 8
// 426.871 us; speedup vs baseline: 9.4718x; 2.0548x over previous
//
#include <hip/hip_runtime.h>
#include <math.h>

#define N_NODES 60
#define N_EDGES 1800
#define N_ETOT  1860
#define SLOPE   0.2f

// ---------------- LDS union: conv path vs gnn path (block 0) ----------------
// conv layout: simg[2 img][3 ic][32 y][32 x]  (6144 f)
//              c1  [2 img][6 ic][14 y][16 x]  (2688 f, x padded 14->16)
struct ConvS {
    float simg[2 * 3 * 32 * 32];
    float c1[2 * 6 * 14 * 16];
    float pad[16];               // absorbs halo over-reads
};
struct GnnS {
    float ea[N_ETOT];
    float alpha[N_ETOT];         // becomes exp() in place
    float x_in[960];
    float xl[960];
    float outb[960];
    float as_[N_NODES], ad_[N_NODES], den_[N_NODES];
    float red[256];
    unsigned char srcs[N_ETOT], dsts[N_ETOT];
    unsigned short csr[N_ETOT];
    int cnt[N_NODES], off[N_NODES + 4];
};
union SMem { ConvS c; GnnS g; };

__device__ __forceinline__ void block_reduce_sum(float v, float* red, float* out) {
    int tid = threadIdx.x;
    red[tid] = v;
    __syncthreads();
    for (int st = 128; st > 0; st >>= 1) {
        if (tid < st) red[tid] += red[tid + st];
        __syncthreads();
    }
    *out = red[0];
    __syncthreads();
}

__device__ void gat_layer(GnnS& S, const float* x_in, int in_dim, int out_dim,
                          const float* W, const float* a_src, const float* a_dst,
                          const float* We, const float* a_edge, const float* bias,
                          float* xl, float* outb) {
    const int tid = threadIdx.x, nt = blockDim.x;
    for (int idx = tid; idx < N_NODES * out_dim; idx += nt) {
        int i = idx / out_dim, j = idx % out_dim;
        float s = 0.f;
        for (int k = 0; k < in_dim; ++k) s += x_in[i * in_dim + k] * W[k * out_dim + j];
        xl[idx] = s;
    }
    __syncthreads();
    for (int i = tid; i < N_NODES; i += nt) {
        float s = 0.f, d = 0.f;
        for (int j = 0; j < out_dim; ++j) {
            s += xl[i * out_dim + j] * a_src[j];
            d += xl[i * out_dim + j] * a_dst[j];
        }
        S.as_[i] = s; S.ad_[i] = d;
    }
    float ecoef = 0.f;
    for (int j = 0; j < out_dim; ++j) ecoef += We[j] * a_edge[j];
    __syncthreads();
    for (int e = tid; e < N_ETOT; e += nt) {
        float a = S.as_[S.srcs[e]] + S.ad_[S.dsts[e]] + S.ea[e] * ecoef;
        S.alpha[e] = (a >= 0.f) ? a : SLOPE * a;
    }
    __syncthreads();
    for (int d = tid; d < N_NODES; d += nt) {
        float m = -INFINITY;
        for (int k = S.off[d]; k < S.off[d + 1]; ++k) m = fmaxf(m, S.alpha[S.csr[k]]);
        float den = 0.f;
        for (int k = S.off[d]; k < S.off[d + 1]; ++k) {
            int e = S.csr[k];
            float ex = expf(S.alpha[e] - m);
            S.alpha[e] = ex;
            den += ex;
        }
        S.den_[d] = den;
    }
    __syncthreads();
    for (int idx = tid; idx < N_NODES * out_dim; idx += nt) {
        int d = idx / out_dim, j = idx % out_dim;
        float s = 0.f;
        for (int k = S.off[d]; k < S.off[d + 1]; ++k) {
            int e = S.csr[k];
            s += S.alpha[e] * xl[(int)S.srcs[e] * out_dim + j];
        }
        outb[idx] = s / S.den_[d] + bias[j];
    }
    __syncthreads();
}

__device__ void bn_relu(GnnS& S, const float* v, float* dst, int n) {
    const int tid = threadIdx.x, nt = blockDim.x;
    float s = 0.f;
    for (int i = tid; i < n; i += nt) s += v[i];
    float tot;
    block_reduce_sum(s, S.red, &tot);
    float avg = tot / n;
    float s2 = 0.f;
    for (int i = tid; i < n; i += nt) { float d = v[i] - avg; s2 += d * d; }
    block_reduce_sum(s2, S.red, &tot);
    float stdv = sqrtf(tot / n);
    for (int i = tid; i < n; i += nt) dst[i] = fmaxf((v[i] - avg) / stdv, 0.f);
    __syncthreads();
}

__device__ void gnn_path(GnnS& S,
    const float* node_fea, const float* edge_fea, const int* eidx,
    const float* g1w, const float* g1as, const float* g1ad,
    const float* g1we, const float* g1ae, const float* g1b,
    const float* g2w, const float* g2as, const float* g2ad,
    const float* g2we, const float* g2ae, const float* g2b,
    const float* fc1w, const float* fc1b, float* gcontrib) {
    const int tid = threadIdx.x, nt = blockDim.x;
    float s = 0.f;
    for (int e = tid; e < N_EDGES; e += nt) s += edge_fea[e];
    float tot;
    block_reduce_sum(s, S.red, &tot);
    float emean = tot / N_EDGES;
    for (int e = tid; e < N_ETOT; e += nt) {
        if (e < N_EDGES) {
            S.ea[e] = edge_fea[e];
            S.srcs[e] = (unsigned char)eidx[e];
            S.dsts[e] = (unsigned char)eidx[N_EDGES + e];
        } else {
            S.ea[e] = emean;
            S.srcs[e] = (unsigned char)(e - N_EDGES);
            S.dsts[e] = (unsigned char)(e - N_EDGES);
        }
    }
    if (tid < N_NODES) S.x_in[tid] = node_fea[tid];
    __syncthreads();
    if (tid < N_NODES) {
        int c = 0;
        for (int e = 0; e < N_ETOT; ++e) c += (S.dsts[e] == tid);
        S.cnt[tid] = c;
    }
    __syncthreads();
    if (tid == 0) {
        S.off[0] = 0;
        for (int d = 0; d < N_NODES; ++d) S.off[d + 1] = S.off[d] + S.cnt[d];
    }
    __syncthreads();
    if (tid < N_NODES) {
        int k = S.off[tid];
        for (int e = 0; e < N_ETOT; ++e)
            if (S.dsts[e] == tid) S.csr[k++] = (unsigned short)e;
    }
    __syncthreads();

    gat_layer(S, S.x_in, 1, 6, g1w, g1as, g1ad, g1we, g1ae, g1b, S.xl, S.outb);
    bn_relu(S, S.outb, S.x_in, N_NODES * 6);
    gat_layer(S, S.x_in, 6, 16, g2w, g2as, g2ad, g2we, g2ae, g2b, S.xl, S.outb);
    bn_relu(S, S.outb, S.x_in, N_NODES * 16);   // x_in[0..959] == g

    for (int j = tid; j < 512; j += nt) {
        float acc = fc1b[j];
#pragma unroll 4
        for (int k = 0; k < 960; ++k) acc += S.x_in[k] * fc1w[(size_t)k * 512 + j];
        gcontrib[j] = acc;
    }
}

// ---------------------------------------------------------------------------
// conv path. Block = 256 threads = 4 waves, 2 images.
// Lane-consecutive LDS addressing (R3: conflicts ~0).
// ic/ky loops: unroll 1 (bounds weight live-set — R4 spilled with full unroll).
// j/t loops: FULL unroll — acc[] must be compile-time-indexed; partial unroll
// sent acc to scratch (R7: VGPR=60, 2.4GB scratch writes; rule #20).
// ---------------------------------------------------------------------------
__device__ void conv_path(ConvS& C, int img0,
                          const float* __restrict__ pic,
                          const float* __restrict__ w1, const float* __restrict__ b1,
                          const float* __restrict__ w2, const float* __restrict__ b2,
                          float* __restrict__ p) {
    const int tid = threadIdx.x;
    const int w = tid >> 6, lane = tid & 63;

    // stage 2 images (coalesced float4; LDS writes lane-consecutive => no conflict)
    {
        const float4* src = (const float4*)(pic + (size_t)img0 * 3072);
        float4* dst = (float4*)C.simg;
        for (int i = tid; i < 1536; i += 256) dst[i] = src[i];
    }
    __syncthreads();

    // ---------------- conv1: [3,32,32] -> pool -> c1[6,14,16] ----------------
    // wave w: img = w>>1, handles ypairs {half, half+2, ..., half+12}, half = w&1
    {
        const int img = w >> 1, half = w & 1;
        const int y_rel = lane >> 5, x = lane & 31;
        const float* S = C.simg + img * 3072;
        float acc[7][6];
#pragma unroll
        for (int j = 0; j < 7; ++j)
#pragma unroll
            for (int oc = 0; oc < 6; ++oc) acc[j][oc] = b1[oc];

#pragma unroll 1
        for (int ic = 0; ic < 3; ++ic)
#pragma unroll 1
            for (int ky = 0; ky < 5; ++ky) {
                float wv[6][5];
#pragma unroll
                for (int oc = 0; oc < 6; ++oc)
#pragma unroll
                    for (int kx = 0; kx < 5; ++kx)
                        wv[oc][kx] = w1[(oc * 3 + ic) * 25 + ky * 5 + kx];
                const float* Sc = S + ic * 1024 + x;
#pragma unroll
                for (int j = 0; j < 7; ++j) {
                    int row = 2 * (half + 2 * j) + y_rel + ky;   // <= 31
                    const float* rp = Sc + row * 32;
                    float v0 = rp[0], v1 = rp[1], v2 = rp[2], v3 = rp[3], v4 = rp[4];
#pragma unroll
                    for (int oc = 0; oc < 6; ++oc)
                        acc[j][oc] += v0 * wv[oc][0] + v1 * wv[oc][1] + v2 * wv[oc][2]
                                    + v3 * wv[oc][3] + v4 * wv[oc][4];
                }
            }
        // pool 2x2 (x-pair via xor1, y-pair via xor32) + relu, write c1
#pragma unroll
        for (int j = 0; j < 7; ++j) {
            int yp = half + 2 * j;
#pragma unroll
            for (int oc = 0; oc < 6; ++oc) {
                float v = acc[j][oc];
                v = fmaxf(v, __shfl_xor(v, 1, 64));
                v = fmaxf(v, __shfl_xor(v, 32, 64));
                v = fmaxf(v, 0.f);
                if (y_rel == 0 && (x & 1) == 0 && x < 28)
                    C.c1[((img * 6 + oc) * 14 + yp) * 16 + (x >> 1)] = v;
            }
        }
    }
    __syncthreads();

    // ---------------- conv2: c1[6,14,16] -> pool -> p[16,5,5] ----------------
    // wave w: img = w>>1, oc-half = w&1; 3 row-tasks (conv rows 4t..4t+3)
    {
        const int img = w >> 1, och = w & 1;
        const int y_rel = lane >> 4, x = lane & 15;
        const float* C1 = C.c1 + img * (6 * 14 * 16);
        float acc[3][8];
#pragma unroll
        for (int t = 0; t < 3; ++t)
#pragma unroll
            for (int o = 0; o < 8; ++o) acc[t][o] = b2[och * 8 + o];

#pragma unroll 1
        for (int ic = 0; ic < 6; ++ic)
#pragma unroll 1
            for (int ky = 0; ky < 5; ++ky) {
                float wv[8][5];
#pragma unroll
                for (int o = 0; o < 8; ++o)
#pragma unroll
                    for (int kx = 0; kx < 5; ++kx)
                        wv[o][kx] = w2[((och * 8 + o) * 6 + ic) * 25 + ky * 5 + kx];
                const float* Cc = C1 + ic * 224 + x;
#pragma unroll
                for (int t = 0; t < 3; ++t) {
                    int row = 4 * t + y_rel + ky;
                    row = (row < 14) ? row : 13;                 // clamp garbage lanes
                    const float* rp = Cc + row * 16;
                    float v0 = rp[0], v1 = rp[1], v2 = rp[2], v3 = rp[3], v4 = rp[4];
#pragma unroll
                    for (int o = 0; o < 8; ++o)
                        acc[t][o] += v0 * wv[o][0] + v1 * wv[o][1] + v2 * wv[o][2]
                                   + v3 * wv[o][3] + v4 * wv[o][4];
                }
            }
        // pool 2x2 (x-pair xor1, y-pair xor16) + relu, write p (global)
#pragma unroll
        for (int t = 0; t < 3; ++t) {
#pragma unroll
            for (int o = 0; o < 8; ++o) {
                float v = acc[t][o];
                v = fmaxf(v, __shfl_xor(v, 1, 64));
                v = fmaxf(v, __shfl_xor(v, 16, 64));
                v = fmaxf(v, 0.f);
                int py = 2 * t + (y_rel >> 1);
                if ((y_rel & 1) == 0 && (x & 1) == 0 && x < 10 && py < 5) {
                    int oc = och * 8 + o;
                    p[((size_t)(img0 + img) * 16 + oc) * 25 + py * 5 + (x >> 1)] = v;
                }
            }
        }
    }
}

// launch_bounds(256,4): VGPR cap = 512/4 = 128, matching the LDS-capped
// occupancy (4 blocks/CU); R7 showed letting the allocator pick is unstable.
__global__ void __launch_bounds__(256, 4) fused_kernel(
    const float* __restrict__ node_fea, const float* __restrict__ edge_fea,
    const int* __restrict__ eidx,
    const float* g1w, const float* g1as, const float* g1ad,
    const float* g1we, const float* g1ae, const float* g1b,
    const float* g2w, const float* g2as, const float* g2ad,
    const float* g2we, const float* g2ae, const float* g2b,
    const float* __restrict__ fc1w, const float* __restrict__ fc1b,
    float* __restrict__ gcontrib,
    const float* __restrict__ pic,
    const float* __restrict__ c1w, const float* __restrict__ c1b,
    const float* __restrict__ c2w, const float* __restrict__ c2b,
    float* __restrict__ p) {
    __shared__ SMem u;
    if (blockIdx.x == 0) {
        gnn_path(u.g, node_fea, edge_fea, eidx,
                 g1w, g1as, g1ad, g1we, g1ae, g1b,
                 g2w, g2as, g2ad, g2we, g2ae, g2b,
                 fc1w, fc1b, gcontrib);
    } else {
        conv_path(u.c, (blockIdx.x - 1) * 2, pic, c1w, c1b, c2w, c2b, p);
    }
}

// ---------------------------------------------------------------------------
// FC1: h[b,j] = relu(gcontrib[j] + sum_k p[b,k]*w2[k,j]); w2 = fc1_w[960:,:]
// ---------------------------------------------------------------------------
#define FC1_ROWS 16
__global__ void fc1_kernel(
    const float* __restrict__ p, const float* __restrict__ w,
    const float* __restrict__ gcontrib, float* __restrict__ h) {
    __shared__ float sp[FC1_ROWS * 400];
    const int tid = threadIdx.x;
    const size_t r0 = (size_t)blockIdx.x * FC1_ROWS;
    for (int i = tid; i < FC1_ROWS * 400; i += 256) sp[i] = p[r0 * 400 + i];
    __syncthreads();
    const int c0 = tid, c1 = tid + 256;
    float acc[FC1_ROWS][2];
#pragma unroll
    for (int r = 0; r < FC1_ROWS; ++r) { acc[r][0] = 0.f; acc[r][1] = 0.f; }
    for (int k = 0; k < 400; k += 4) {
        float wa0 = w[(size_t)(k + 0) * 512 + c0], wa1 = w[(size_t)(k + 0) * 512 + c1];
        float wb0 = w[(size_t)(k + 1) * 512 + c0], wb1 = w[(size_t)(k + 1) * 512 + c1];
        float wc0 = w[(size_t)(k + 2) * 512 + c0], wc1 = w[(size_t)(k + 2) * 512 + c1];
        float wd0 = w[(size_t)(k + 3) * 512 + c0], wd1 = w[(size_t)(k + 3) * 512 + c1];
#pragma unroll
        for (int r = 0; r < FC1_ROWS; ++r) {
            float4 pv = *(const float4*)&sp[r * 400 + k];
            acc[r][0] += pv.x * wa0 + pv.y * wb0 + pv.z * wc0 + pv.w * wd0;
            acc[r][1] += pv.x * wa1 + pv.y * wb1 + pv.z * wc1 + pv.w * wd1;
        }
    }
    float g0 = gcontrib[c0], g1 = gcontrib[c1];
#pragma unroll
    for (int r = 0; r < FC1_ROWS; ++r) {
        h[(r0 + r) * 512 + c0] = fmaxf(acc[r][0] + g0, 0.f);
        h[(r0 + r) * 512 + c1] = fmaxf(acc[r][1] + g1, 0.f);
    }
}

// ---------------------------------------------------------------------------
// FC2: out[b,j] = tanh(sum_k h[b,k]*fc2_w[k,j] + fc2_b[j]); one wave per row
// ---------------------------------------------------------------------------
__global__ void fc2_kernel(
    const float* __restrict__ h, const float* __restrict__ w,
    const float* __restrict__ b, float* __restrict__ out) {
    const int wave = threadIdx.x >> 6, lane = threadIdx.x & 63;
    const size_t row = (size_t)blockIdx.x * 4 + wave;
    const float* hr = h + row * 512;
    float partial[10];
#pragma unroll
    for (int j = 0; j < 10; ++j) partial[j] = 0.f;
    for (int k = lane; k < 512; k += 64) {
        float hv = hr[k];
        const float* wr = w + (size_t)k * 10;
#pragma unroll
        for (int j = 0; j < 10; ++j) partial[j] += hv * wr[j];
    }
#pragma unroll
    for (int j = 0; j < 10; ++j) {
        float v = partial[j];
        for (int sft = 32; sft > 0; sft >>= 1) v += __shfl_xor(v, sft, 64);
        partial[j] = v;
    }
    if (lane == 0) {
#pragma unroll
        for (int j = 0; j < 10; ++j)
            out[row * 10 + j] = tanhf(partial[j] + b[j]);
    }
}

extern "C" void kernel_launch(void* const* d_in, const int* in_sizes, int n_in,
                              void* d_out, int out_size, void* d_ws, size_t ws_size,
                              hipStream_t stream) {
    const float* node_fea = (const float*)d_in[0];
    const float* edge_fea = (const float*)d_in[1];
    const float* pic      = (const float*)d_in[2];
    const float* c1w = (const float*)d_in[3];
    const float* c1b = (const float*)d_in[4];
    const float* c2w = (const float*)d_in[5];
    const float* c2b = (const float*)d_in[6];
    const float* g1w  = (const float*)d_in[7];
    const float* g1as = (const float*)d_in[8];
    const float* g1ad = (const float*)d_in[9];
    const float* g1we = (const float*)d_in[10];
    const float* g1ae = (const float*)d_in[11];
    const float* g1b  = (const float*)d_in[12];
    const float* g2w  = (const float*)d_in[13];
    const float* g2as = (const float*)d_in[14];
    const float* g2ad = (const float*)d_in[15];
    const float* g2we = (const float*)d_in[16];
    const float* g2ae = (const float*)d_in[17];
    const float* g2b  = (const float*)d_in[18];
    const float* fc1w = (const float*)d_in[19];
    const float* fc1b = (const float*)d_in[20];
    const float* fc2w = (const float*)d_in[21];
    const float* fc2b = (const float*)d_in[22];
    const int*   eidx = (const int*)d_in[23];
    float* out = (float*)d_out;

    char* ws = (char*)d_ws;
    float* gcontrib = (float*)ws;                                   // 512 f
    float* p = (float*)(ws + 2048);                                 // 8192*400 f
    float* h = (float*)(ws + 2048 + (size_t)8192 * 400 * 4);        // 8192*512 f

    hipLaunchKernelGGL(fused_kernel, dim3(4097), dim3(256), 0, stream,
                       node_fea, edge_fea, eidx,
                       g1w, g1as, g1ad, g1we, g1ae, g1b,
                       g2w, g2as, g2ad, g2we, g2ae, g2b,
                       fc1w, fc1b, gcontrib,
                       pic, c1w, c1b, c2w, c2b, p);
    hipLaunchKernelGGL(fc1_kernel, dim3(8192 / FC1_ROWS), dim3(256), 0, stream,
                       p, fc1w + (size_t)960 * 512, gcontrib, h);
    hipLaunchKernelGGL(fc2_kernel, dim3(8192 / 4), dim3(256), 0, stream,
                       h, fc2w, fc2b, out);
}